// Round 14
// baseline (605.021 us; speedup 1.0000x reference)
//
#include <hip/hip_runtime.h>
#include <stdint.h>

// ============================================================================
// PopularNicheGraphBuilder: segment-sums -> normalize -> per-row db3 DWT stats
// (in LDS) -> exact replication of jax.random.beta (threefry + Marsaglia-Tsang
// log-space gamma).
//
// Round 14 (on r13): BUCKETED FILL. r13 showed the klist scatter's 14x write
// amplification is structural (lines shared across non-coherent per-XCD L2s).
// Fix: one WG per bucket of 128 rows builds its klist region fully in LDS
// (scan input array -> LDS-atomic append), then dumps region + counts as
// DENSE contiguous writes. No global atomics, writes 114 -> ~19 MB. List
// order within a row changes, but all consumers are order-invariant
// (max-k dedup, int64 sums, counts) -> bit-identical outputs. klists back to
// row-major (readers coalesced, r12 indexing).
// ============================================================================
#define PARTITIONABLE 1

typedef unsigned long long ull;

#define NUM_U 16384
#define NUM_I 8192
#define CAP_U 160
#define CAP_I 256

#define IB_ROWS 128
#define UB_ROWS 128
#define N_IBUCKET (NUM_I / IB_ROWS)   // 64
#define N_UBUCKET (NUM_U / UB_ROWS)   // 128

// output layout
#define OFF_UPW 0
#define OFF_UMW 16384
#define OFF_IPW 32768
#define OFF_IMW 40960
#define OFF_ACT 49152
#define OFF_POP 65536

// ---------------- threefry2x32 ----------------
struct K2 { uint32_t a, b; };

__host__ __device__ inline void tf2x32(uint32_t k0, uint32_t k1, uint32_t& x0, uint32_t& x1) {
  const uint32_t ks2 = k0 ^ k1 ^ 0x1BD11BDAu;
  x0 += k0; x1 += k1;
#define TF_R(r) { x0 += x1; x1 = (x1 << (r)) | (x1 >> (32 - (r))); x1 ^= x0; }
  TF_R(13) TF_R(15) TF_R(26) TF_R(6)
  x0 += k1; x1 += ks2 + 1u;
  TF_R(17) TF_R(29) TF_R(16) TF_R(24)
  x0 += ks2; x1 += k0 + 2u;
  TF_R(13) TF_R(15) TF_R(26) TF_R(6)
  x0 += k0; x1 += k1 + 3u;
  TF_R(17) TF_R(29) TF_R(16) TF_R(24)
  x0 += k1; x1 += ks2 + 4u;
  TF_R(13) TF_R(15) TF_R(26) TF_R(6)
  x0 += ks2; x1 += k0 + 5u;
#undef TF_R
}

__host__ __device__ inline K2 tf_enc(K2 k, uint32_t x0, uint32_t x1) {
  tf2x32(k.a, k.b, x0, x1);
  K2 r; r.a = x0; r.b = x1; return r;
}

// split(key) -> 2 children
__host__ __device__ inline void split2(K2 k, K2& c0, K2& c1) {
#if PARTITIONABLE
  c0 = tf_enc(k, 0u, 0u);
  c1 = tf_enc(k, 0u, 1u);
#else
  K2 p = tf_enc(k, 0u, 2u);
  K2 q = tf_enc(k, 1u, 3u);
  c0.a = p.a; c0.b = q.a;
  c1.a = p.b; c1.b = q.b;
#endif
}

// split(key, 3)
__device__ inline void split3(K2 k, K2& c0, K2& c1, K2& c2) {
#if PARTITIONABLE
  c0 = tf_enc(k, 0u, 0u);
  c1 = tf_enc(k, 0u, 1u);
  c2 = tf_enc(k, 0u, 2u);
#else
  K2 p = tf_enc(k, 0u, 3u);
  K2 q = tf_enc(k, 1u, 4u);
  K2 r = tf_enc(k, 2u, 5u);
  c0.a = p.a; c0.b = q.a;
  c1.a = r.a; c1.b = p.b;
  c2.a = q.b; c2.b = r.b;
#endif
}

// scalar random_bits(key, 32, ())
__device__ inline uint32_t draw_bits(K2 k) {
  K2 e = tf_enc(k, 0u, 0u);
#if PARTITIONABLE
  return e.a ^ e.b;
#else
  return e.a;
#endif
}

// split(key, B)[i]
__device__ inline K2 elem_key(K2 k, uint32_t i, uint32_t B) {
#if PARTITIONABLE
  return tf_enc(k, 0u, i);
#else
  if (i < (B >> 1)) {
    K2 p = tf_enc(k, 2u * i, B + 2u * i);
    K2 q = tf_enc(k, 2u * i + 1u, B + 2u * i + 1u);
    K2 r; r.a = p.a; r.b = q.a; return r;
  } else {
    uint32_t j = 2u * i - B;
    K2 p = tf_enc(k, j, 2u * i);
    K2 q = tf_enc(k, j + 1u, 2u * i + 1u);
    K2 r; r.a = p.b; r.b = q.b; return r;
  }
#endif
}

__device__ inline float u01_bits(uint32_t b) {
  return __uint_as_float((b >> 9) | 0x3F800000u) - 1.0f;
}

// XLA ErfInv32 (Giles polynomial) -- matches lax.erf_inv on f32
__device__ inline float erfinv_f32(float x) {
  float w = -log1pf(-x * x);
  float p;
  if (w < 5.0f) {
    w = w - 2.5f;
    p = 2.81022636e-08f;
    p = fmaf(p, w, 3.43273939e-07f);
    p = fmaf(p, w, -3.5233877e-06f);
    p = fmaf(p, w, -4.39150654e-06f);
    p = fmaf(p, w, 0.00021858087f);
    p = fmaf(p, w, -0.00125372503f);
    p = fmaf(p, w, -0.00417768164f);
    p = fmaf(p, w, 0.246640727f);
    p = fmaf(p, w, 1.50140941f);
  } else {
    w = sqrtf(w) - 3.0f;
    p = -0.000200214257f;
    p = fmaf(p, w, 0.000100950558f);
    p = fmaf(p, w, 0.00134934322f);
    p = fmaf(p, w, -0.00367342844f);
    p = fmaf(p, w, 0.00573950773f);
    p = fmaf(p, w, -0.0076224613f);
    p = fmaf(p, w, 0.00943887047f);
    p = fmaf(p, w, 1.00167406f);
    p = fmaf(p, w, 2.83297682f);
  }
  return p * x;
}

// jax _gamma_one with log_space=True (Marsaglia-Tsang + boost)
__device__ float log_gamma_sample(K2 key, float alpha_orig) {
  const bool boost = (alpha_orig >= 1.0f);
  const float alpha = boost ? alpha_orig : (alpha_orig + 1.0f);
  const float d = alpha - 0.33333334f;
  const float c = 0.33333334f / sqrtf(d);

  K2 k0, sub;
  split2(key, k0, sub);
  const float u_boost = u01_bits(draw_bits(sub));

  K2 kcur = k0;
  float X = 0.0f, V = 1.0f, U = 2.0f;
  while ((U >= 1.0f - 0.0331f * (X * X)) &&
         (logf(U) >= X * 0.5f + d * ((1.0f - V) + logf(V)))) {
    K2 knext, xk, Uk;
    split3(kcur, knext, xk, Uk);
    kcur = knext;
    float x, v;
    K2 ik = xk;
    do {
      K2 in0, isub;
      split2(ik, in0, isub);
      ik = in0;
      float f = u01_bits(draw_bits(isub));
      // uniform(lo=nextafter(-1,0), hi=1): (hi-lo) rounds to exactly 2.0f
      float u = fmaxf(-0.99999994f, f * 2.0f + (-0.99999994f));
      x = 1.41421356f * erfinv_f32(u);   // sqrt(2) as f32
      v = 1.0f + x * c;
    } while (v <= 0.0f);
    X = x * x;
    V = (v * v) * v;
    U = u01_bits(draw_bits(Uk));
  }
  float lg = logf(d * V);
  if (!boost) lg += log1pf(-u_boost) / alpha_orig;
  return lg;
}

// ---------------- pipeline kernels ----------------

__global__ __launch_bounds__(256) void init_kernel(ull* __restrict__ nrm2pair) {
  int i = threadIdx.x;
  if (i < 2) nrm2pair[i] = 0ull;
}

// One workgroup per bucket: blocks [0, N_IBUCKET) handle item buckets,
// the rest handle user buckets. Scan the full index array, LDS-append
// entries for owned rows, then dump the klist region + counts densely.
__global__ __launch_bounds__(256) void bucket_fill_kernel(
    const int* __restrict__ user, const int* __restrict__ item, int n,
    int* __restrict__ fu, int* __restrict__ fi,
    uint32_t* __restrict__ lu, uint32_t* __restrict__ li) {
  extern __shared__ uint32_t lsm[];
  const int bid = blockIdx.x;
  const int tid = threadIdx.x;
  const bool is_item = bid < N_IBUCKET;
  const int rows = is_item ? IB_ROWS : UB_ROWS;
  const int cap = is_item ? CAP_I : CAP_U;
  const int base = is_item ? bid * IB_ROWS : (bid - N_IBUCKET) * UB_ROWS;
  const int* __restrict__ src = is_item ? item : user;
  uint32_t* cnt = lsm;            // rows
  uint32_t* list = lsm + rows;    // rows * cap

  for (int i = tid; i < rows; i += 256) cnt[i] = 0u;
  __syncthreads();

  const int4* src4 = (const int4*)src;
  const int n4 = n >> 2;
  // 2-deep software pipeline on the streaming loads
  int k4 = tid;
  if (k4 < n4) {
    int4 v = src4[k4];
    for (;;) {
      int kn = k4 + 256;
      int4 vn;
      if (kn < n4) vn = src4[kn];
      int k0 = k4 << 2;
      int r0 = v.x - base, r1 = v.y - base, r2 = v.z - base, r3 = v.w - base;
      if ((unsigned)r0 < (unsigned)rows) { uint32_t q = atomicAdd(&cnt[r0], 1u); if ((int)q < cap) list[r0 * cap + (int)q] = (uint32_t)k0; }
      if ((unsigned)r1 < (unsigned)rows) { uint32_t q = atomicAdd(&cnt[r1], 1u); if ((int)q < cap) list[r1 * cap + (int)q] = (uint32_t)(k0 + 1); }
      if ((unsigned)r2 < (unsigned)rows) { uint32_t q = atomicAdd(&cnt[r2], 1u); if ((int)q < cap) list[r2 * cap + (int)q] = (uint32_t)(k0 + 2); }
      if ((unsigned)r3 < (unsigned)rows) { uint32_t q = atomicAdd(&cnt[r3], 1u); if ((int)q < cap) list[r3 * cap + (int)q] = (uint32_t)(k0 + 3); }
      if (kn >= n4) break;
      k4 = kn; v = vn;
    }
  }
  for (int k = (n4 << 2) + tid; k < n; k += 256) {
    int r = src[k] - base;
    if ((unsigned)r < (unsigned)rows) { uint32_t q = atomicAdd(&cnt[r], 1u); if ((int)q < cap) list[r * cap + (int)q] = (uint32_t)k; }
  }
  __syncthreads();

  // dense dumps: klist region (contiguous) + counts
  uint32_t* gl = (is_item ? li : lu) + (size_t)base * cap;
  const int w4 = (rows * cap) >> 2;
  int4* gl4 = (int4*)gl;
  const int4* ls4 = (const int4*)list;
  for (int i = tid; i < w4; i += 256) gl4[i] = ls4[i];
  int* fc = (is_item ? fi : fu) + base;
  for (int i = tid; i < rows; i += 256) fc[i] = (int)cnt[i];
}

// one wave per item: exact int64 fixed-point sum of values over the item list.
// Writes RAW pop (normalization applied inline by consumers).
__global__ __launch_bounds__(256) void pop_wave_kernel(
    const int* __restrict__ fi, const uint32_t* __restrict__ li,
    const float* __restrict__ values,
    float* __restrict__ pop, double* __restrict__ nrm2) {
  __shared__ float red[4];
  int lane = threadIdx.x & 63, wid = threadIdx.x >> 6;
  int i = blockIdx.x * 4 + wid;
  int cnt = fi[i];
  int cr = cnt < CAP_I ? cnt : CAP_I;
  long long s = 0;
  for (int e = lane; e < cr; e += 64)
    s += (long long)llrintf(values[li[(size_t)i * CAP_I + e]] * 4294967296.0f);
  for (int o = 32; o > 0; o >>= 1) s += __shfl_down(s, o);
  if (lane == 0) {
    float svf = (float)((double)(ull)s * (1.0 / 4294967296.0));
    float p = svf * log1pf((float)cnt);
    pop[i] = p;
    red[wid] = p * p;
  }
  __syncthreads();
  if (threadIdx.x == 0)
    atomicAdd(nrm2, (double)(red[0] + red[1] + red[2] + red[3]));
}

// one wave per user: exact int64 fixed-point sum of act terms over the list.
// pop is RAW; normalized inline with the exact pop_norm expression.
__global__ __launch_bounds__(256) void act_wave_kernel(
    const int* __restrict__ fu, const uint32_t* __restrict__ lu,
    const int* __restrict__ item, const float* __restrict__ values,
    const float* __restrict__ pop, const double* __restrict__ nrm2_pop,
    float* __restrict__ act, double* __restrict__ nrm2) {
  __shared__ float red[4];
  int lane = threadIdx.x & 63, wid = threadIdx.x >> 6;
  int u = blockIdx.x * 4 + wid;
  int cnt = fu[u];
  int cr = cnt < CAP_U ? cnt : CAP_U;
  const float nrmp = sqrtf((float)(*nrm2_pop));
  const float dnp = nrmp + 1e-8f;
  long long s = 0;
  for (int e = lane; e < cr; e += 64) {
    uint32_t k = lu[(size_t)u * CAP_U + e];
    float pn = pop[item[k]] / dnp;                 // == pop_norm's v, bit-identical
    float term = values[k] / log1pf(pn + 1e-8f);
    s += (long long)llrintf(term * 16777216.0f);
  }
  for (int o = 32; o > 0; o >>= 1) s += __shfl_down(s, o);
  if (lane == 0) {
    float a = (float)((double)(ull)s * (1.0 / 16777216.0));
    act[u] = a;
    red[wid] = a * a;
  }
  __syncthreads();
  if (threadIdx.x == 0)
    atomicAdd(nrm2, (double)(red[0] + red[1] + red[2] + red[3]));
}

// ---------------- bit tricks ----------------
__device__ inline uint32_t evencomp(uint32_t x) {
  x = (x | (x >> 1)) & 0x55555555u;
  x = (x | (x >> 1)) & 0x33333333u;
  x = (x | (x >> 2)) & 0x0F0F0F0Fu;
  x = (x | (x >> 4)) & 0x00FF00FFu;
  x = (x | (x >> 8)) & 0x0000FFFFu;
  return x;
}
template <int NWIN>
__device__ inline uint32_t hword(const uint32_t* B, int i) {
  uint32_t a = (2 * i < NWIN) ? B[2 * i] : 0u;
  uint32_t b = (2 * i + 1 < NWIN) ? B[2 * i + 1] : 0u;
  return evencomp(a) | (evencomp(b) << 16);
}
template <int NWIN>
__device__ inline uint32_t tword(const uint32_t* B, int w) {
  uint32_t h = hword<NWIN>(B, w);
  uint32_t hp = (w > 0) ? hword<NWIN>(B, w - 1) : 0u;
  return h | (h << 1) | (h << 2) | (hp >> 31) | (hp >> 30);
}

// block-wide popcount prefix scan; entry+exit barriers inside. Returns total.
template <int NWORDS>
__device__ inline int scan_bits(const uint32_t* __restrict__ W, uint16_t* __restrict__ P,
                                int tid, int* __restrict__ isc, int* __restrict__ tot) {
  constexpr int WPT = (NWORDS + 255) / 256;
  __syncthreads();
  uint32_t w[WPT];
  int v = 0;
#pragma unroll
  for (int j = 0; j < WPT; ++j) {
    int idx = tid * WPT + j;
    w[j] = (idx < NWORDS) ? W[idx] : 0u;
    v += __popc(w[j]);
  }
  int lane = tid & 63, wid = tid >> 6;
  int incl = v;
  for (int off = 1; off < 64; off <<= 1) {
    int y = __shfl_up(incl, off, 64);
    if (lane >= off) incl += y;
  }
  if (lane == 63) isc[wid] = incl;
  __syncthreads();
  int base = 0;
  for (int ww = 0; ww < wid; ++ww) base += isc[ww];
  int run = base + incl - v;
#pragma unroll
  for (int j = 0; j < WPT; ++j) {
    int idx = tid * WPT + j;
    if (idx < NWORDS) P[idx] = (uint16_t)run;
    run += __popc(w[j]);
  }
  if (tid == 255) *tot = run;
  __syncthreads();
  return *tot;
}

// invert (T,P) into a worklist of touched positions, ascending
template <int NWORDS>
__device__ inline void build_wl(const uint32_t* __restrict__ T, const uint16_t* __restrict__ P,
                                uint16_t* __restrict__ wl, int tid) {
  for (int w = tid; w < NWORDS; w += 256) {
    uint32_t bits = T[w];
    int r0 = P[w], i = 0;
    while (bits) {
      int b = __ffs(bits) - 1; bits &= bits - 1u;
      wl[r0 + i] = (uint16_t)((w << 5) + b);
      ++i;
    }
  }
}

// 6-tap gather at output m from (bitmap B, prefix P, compacted values V)
template <int NIN>
__device__ inline void gather6(const uint32_t* __restrict__ B, const uint16_t* __restrict__ P,
                               const float* __restrict__ V, int m,
                               float& lo_o, float& hi_o) {
  int c0 = 2 * m - 4; c0 = c0 < 0 ? 0 : c0;
  int c1 = 2 * m + 1; c1 = c1 > NIN - 1 ? NIN - 1 : c1;
  int w0 = c0 >> 5, w1 = c1 >> 5;
  uint32_t b0 = B[w0];
  uint32_t mlo = ~((1u << (c0 & 31)) - 1u);
  uint32_t mhi = (uint32_t)(((uint64_t)1u << ((c1 & 31) + 1)) - 1u);
  uint32_t sel0, sel1; uint32_t b1 = 0;
  if (w1 == w0) { sel0 = b0 & mlo & mhi; sel1 = 0u; }
  else { b1 = B[w1]; sel0 = b0 & mlo; sel1 = b1 & mhi; }
  float tv0 = 0.0f, tv1 = 0.0f, tv2 = 0.0f, tv3 = 0.0f, tv4 = 0.0f, tv5 = 0.0f;
  int tp1 = 2 * m + 1;
  uint32_t s = sel0;
  while (s) {
    int b = __ffs(s) - 1; s &= s - 1u;
    int c = (w0 << 5) + b;
    int idx = (int)P[w0] + __popc(b0 & ((1u << b) - 1u));
    float v = V[idx];
    int t = tp1 - c;
    if (t == 0) tv0 = v; else if (t == 1) tv1 = v; else if (t == 2) tv2 = v;
    else if (t == 3) tv3 = v; else if (t == 4) tv4 = v; else tv5 = v;
  }
  s = sel1;
  while (s) {
    int b = __ffs(s) - 1; s &= s - 1u;
    int c = (w1 << 5) + b;
    int idx = (int)P[w1] + __popc(b1 & ((1u << b) - 1u));
    float v = V[idx];
    int t = tp1 - c;
    if (t == 0) tv0 = v; else if (t == 1) tv1 = v; else if (t == 2) tv2 = v;
    else if (t == 3) tv3 = v; else if (t == 4) tv4 = v; else tv5 = v;
  }
  float lo = 0.0f, hi = 0.0f;
  lo += 0.035226291882100656f * tv0;  hi += -0.3326705529509569f * tv0;
  lo += -0.08544127388224149f * tv1;  hi += 0.8068915093133388f * tv1;
  lo += -0.13501102001039084f * tv2;  hi += -0.4598775021193313f * tv2;
  lo += 0.4598775021193313f * tv3;    hi += -0.13501102001039084f * tv3;
  lo += 0.8068915093133388f * tv4;    hi += 0.08544127388224149f * tv4;
  lo += 0.3326705529509569f * tv5;    hi += 0.035226291882100656f * tv5;
  lo_o = lo; hi_o = hi;
}

__device__ inline int rank_of(const uint32_t* __restrict__ B, const uint16_t* __restrict__ P,
                              int m) {
  int w = m >> 5;
  return (int)P[w] + __popc(B[w] & ((1u << (m & 31)) - 1u));
}

constexpr int align4c(int x) { return (x + 3) & ~3; }
constexpr int cmax(int a, int b) { return a > b ? a : b; }

// LDS bytes for the worklist DWT kernel (mirrors device layout)
constexpr int dwt_shm_bytes(int NCOLS, int M1, int M2, int M3, int CAP) {
  int NW = NCOLS / 32, NW1 = (M1 + 31) / 32, NW2 = (M2 + 31) / 32, NW3 = (M3 + 31) / 32;
  int SZ_RB = cmax(cmax(align4c(NW * 4 + NW * 2), align4c(NW2 * 4 + 4 * CAP * 2)),
                   align4c(5 * CAP * 2));
  int SZ_RC = cmax(align4c(NW1 * 4 + NW1 * 2), align4c(NW3 * 4 + NW3 * 2 + NW2 * 2));
  return (M1 + 12) * 4 + CAP * 4 + SZ_RB + SZ_RC + align4c(3 * CAP * 2) + 64;
}

// per-row 3-level db3 DWT stats, worklist-driven, register-carry staging.
// klist row-major: entry q of row r at klist[r * CAP + q].
// scale_raw + nrm2 -> scale computed inline; tid0 writes out[outoff + r].
template <int NCOLS, int M1, int M2, int M3, int CAP>
__global__ __launch_bounds__(256) void dwt_rows_kernel(
    const uint32_t* __restrict__ klist, const int* __restrict__ rowlen,
    const int* __restrict__ colsrc, const float* __restrict__ values,
    const float* __restrict__ scale_raw, const double* __restrict__ nrm2,
    float* __restrict__ low_out, float* __restrict__ high_out,
    float* __restrict__ out, int outoff) {
  static_assert(CAP <= 256, "register-carry staging requires CAP <= blockDim");
  constexpr int NW = NCOLS / 32;
  constexpr int NW1 = (M1 + 31) / 32;
  constexpr int NW2 = (M2 + 31) / 32;
  constexpr int NW3 = (M3 + 31) / 32;
  constexpr uint32_t MK1 = (M1 & 31) ? ((1u << (M1 & 31)) - 1u) : 0xFFFFFFFFu;
  constexpr uint32_t MK2 = (M2 & 31) ? ((1u << (M2 & 31)) - 1u) : 0xFFFFFFFFu;
  constexpr uint32_t MK3 = (M3 & 31) ? ((1u << (M3 & 31)) - 1u) : 0xFFFFFFFFu;
  constexpr int SZ_RB = cmax(cmax(align4c(NW * 4 + NW * 2), align4c(NW2 * 4 + 4 * CAP * 2)),
                             align4c(5 * CAP * 2));
  constexpr int SZ_RC = cmax(align4c(NW1 * 4 + NW1 * 2), align4c(NW3 * 4 + NW3 * 2 + NW2 * 2));

  extern __shared__ char smroot[];
  float* buf = (float*)smroot;                       // (M1+12) f; data at +4
  char* pA = smroot + (M1 + 12) * 4;
  int* slot = (int*)pA;                              // CAP (sval aliases)
  float* sval = (float*)pA;
  char* pB = pA + CAP * 4;                           // region B (phase union)
  uint32_t* bitmap = (uint32_t*)pB;                  //   ph1: bitmap NW
  uint16_t* prefix = (uint16_t*)(pB + NW * 4);       //   ph1: prefix NW u16
  uint32_t* T2 = (uint32_t*)pB;                      //   ph2: T2 NW2
  uint16_t* wl2 = (uint16_t*)(pB + NW2 * 4);         //   ph2: wl2 4*CAP u16
  uint16_t* wl3 = (uint16_t*)pB;                     //   ph3: wl3 5*CAP u16
  char* pC = pB + SZ_RB;                             // region C (phase union)
  uint32_t* T1 = (uint32_t*)pC;                      //   ph1: T1 NW1
  uint16_t* p1 = (uint16_t*)(pC + NW1 * 4);          //   ph1: p1 NW1 u16
  uint32_t* T3 = (uint32_t*)pC;                      //   ph2+: T3 NW3
  uint16_t* p3 = (uint16_t*)(pC + NW3 * 4);          //   ph2+: p3 NW3 u16
  uint16_t* p2 = (uint16_t*)(pC + NW3 * 4 + NW3 * 2);//   ph2: p2 NW2 u16
  char* pD = pC + SZ_RC;
  uint16_t* wl1 = (uint16_t*)pD;                     // wl1 3*CAP u16
  char* pE = pD + align4c(3 * CAP * 2);              // 64 B scratch
  int* isc = (int*)pE;                               //   scans: isc[4], tot
  int* tot = isc + 4;
  float* red = (float*)pE;                           //   final: red[16]

  const int r = blockIdx.x;
  const int tid = threadIdx.x;
  // inline normalization (bit-identical to the old norm kernels)
  const float nrm = sqrtf((float)(*nrm2));
  const float snv = scale_raw[r] / (nrm + 1e-8f);
  const float scale = 1.0f + snv;
  if (tid == 0) out[outoff + r] = snv;
  int n = rowlen[r];
  if (n > CAP) n = CAP;

  // s0: init
  {
    constexpr int NB4 = (M1 + 12) / 4;
    float4 z; z.x = 0.0f; z.y = 0.0f; z.z = 0.0f; z.w = 0.0f;
    for (int i = tid; i < NB4; i += 256) ((float4*)buf)[i] = z;
    for (int i = NB4 * 4 + tid; i < M1 + 12; i += 256) buf[i] = 0.0f;
  }
  for (int i = tid; i < NW; i += 256) bitmap[i] = 0u;
  if (tid < CAP) slot[tid] = 0;
  __syncthreads();

  // s1: register-carry staging (<=1 entry per thread) + column bitmap
  const bool have = tid < n;
  uint32_t my_k = 0; int my_c = 0; float my_v = 0.0f;
  if (have) {
    my_k = klist[(size_t)r * CAP + tid];
    my_c = colsrc[my_k];
    my_v = values[my_k] * scale;
    atomicOr(&bitmap[my_c >> 5], 1u << (my_c & 31));
  }
  // s2: prefix over bitmap (entry barrier orders s1)
  scan_bits<NW>(bitmap, prefix, tid, isc, tot);

  // s3: O(n) dedup -- winner = max original index (XLA last-wins scatter)
  int my_rank = 0;
  if (have) {
    my_rank = rank_of(bitmap, prefix, my_c);
    atomicMax(&slot[my_rank], (int)my_k + 1);
  }
  __syncthreads();

  // s4: winner self-writes its value (race-free: unique winner per rank)
  if (have && slot[my_rank] == (int)my_k + 1) sval[my_rank] = my_v;
  // build T1 (masked at M1)
  for (int w = tid; w < NW1; w += 256) {
    uint32_t t = tword<NW>(bitmap, w);
    if (w == NW1 - 1) t &= MK1;
    T1[w] = t;
  }
  // s5: prefix over T1 (entry barrier orders s4)
  const int n1 = scan_bits<NW1>(T1, p1, tid, isc, tot);
  // s6: worklist 1
  build_wl<NW1>(T1, p1, wl1, tid);
  __syncthreads();

  // s7: LEVEL 1 -- worklist gather from (bitmap, prefix, sval) into buf
  float h1 = 0.0f;
  for (int idx = tid; idx < n1; idx += 256) {
    int m = wl1[idx];
    float lo, hi;
    gather6<NCOLS>(bitmap, prefix, sval, m, lo, hi);
    buf[4 + m] = lo;
    h1 += hi * hi;
  }
  __syncthreads();   // buf L1 writes done; bitmap/prefix/sval dead

  // s8: T2 from T1 (region B over the dead bitmap), masked at M2
  for (int w = tid; w < NW2; w += 256) {
    uint32_t t = tword<NW1>(T1, w);
    if (w == NW2 - 1) t &= MK2;
    T2[w] = t;
  }
  // s9: prefix over T2 (entry barrier orders s8)
  const int n2 = scan_bits<NW2>(T2, p2, tid, isc, tot);
  // s10: worklist 2 + T3 from T2 (region C over dead T1), masked at M3
  build_wl<NW2>(T2, p2, wl2, tid);
  for (int w = tid; w < NW3; w += 256) {
    uint32_t t = tword<NW2>(T2, w);
    if (w == NW3 - 1) t &= MK3;
    T3[w] = t;
  }
  __syncthreads();

  // s11: LEVEL 2 -- worklist, in-place batched read->barrier->write
  float h2 = 0.0f;
  {
    int nb = (n2 + 255) >> 8;
    for (int b = 0; b < nb; ++b) {
      int idx = (b << 8) + tid;
      bool ok = idx < n2;
      int m = ok ? wl2[idx] : 0;
      const float* s = buf + 2 * m + 5;
      float x0 = s[0], x1 = s[-1], x2 = s[-2], x3 = s[-3], x4 = s[-4], x5 = s[-5];
      __syncthreads();
      if (ok) {
        float lo = 0.0f, hi = 0.0f;
        lo += 0.035226291882100656f * x0;  hi += -0.3326705529509569f * x0;
        lo += -0.08544127388224149f * x1;  hi += 0.8068915093133388f * x1;
        lo += -0.13501102001039084f * x2;  hi += -0.4598775021193313f * x2;
        lo += 0.4598775021193313f * x3;    hi += -0.13501102001039084f * x3;
        lo += 0.8068915093133388f * x4;    hi += 0.08544127388224149f * x4;
        lo += 0.3326705529509569f * x5;    hi += 0.035226291882100656f * x5;
        buf[4 + m] = lo;
        h2 += hi * hi;
      }
    }
  }
  __syncthreads();
  // stale-clear: level-1 outputs inside [0,M2) not overwritten by level 2
  for (int idx = tid; idx < n1; idx += 256) {
    int m = wl1[idx];
    if (m < M2 && !((T2[m >> 5] >> (m & 31)) & 1u)) buf[4 + m] = 0.0f;
  }
  // stale gap [M2, M2+7]: level-1 outputs beyond level-2's range
  if (tid < 8) buf[4 + M2 + tid] = 0.0f;

  // s12: prefix over T3 (entry barrier orders stale writes)
  const int n3 = scan_bits<NW3>(T3, p3, tid, isc, tot);
  // s13: worklist 3 (region B; T2/p2/wl2 dead)
  build_wl<NW3>(T3, p3, wl3, tid);
  __syncthreads();

  // s14: LEVEL 3 -- worklist, accumulate only
  float h3 = 0.0f, slo = 0.0f;
  for (int idx = tid; idx < n3; idx += 256) {
    int m = wl3[idx];
    const float* s = buf + 2 * m + 5;
    float x0 = s[0], x1 = s[-1], x2 = s[-2], x3 = s[-3], x4 = s[-4], x5 = s[-5];
    float lo = 0.0f, hi = 0.0f;
    lo += 0.035226291882100656f * x0;  hi += -0.3326705529509569f * x0;
    lo += -0.08544127388224149f * x1;  hi += 0.8068915093133388f * x1;
    lo += -0.13501102001039084f * x2;  hi += -0.4598775021193313f * x2;
    lo += 0.4598775021193313f * x3;    hi += -0.13501102001039084f * x3;
    lo += 0.8068915093133388f * x4;    hi += 0.08544127388224149f * x4;
    lo += 0.3326705529509569f * x5;    hi += 0.035226291882100656f * x5;
    slo += lo;
    h3 += hi * hi;
  }

  // s15: reduce
  for (int o = 32; o > 0; o >>= 1) {
    h1 += __shfl_down(h1, o);
    h2 += __shfl_down(h2, o);
    h3 += __shfl_down(h3, o);
    slo += __shfl_down(slo, o);
  }
  __syncthreads();   // all scans done; red may overwrite isc/tot
  int w = tid >> 6, lane = tid & 63;
  if (lane == 0) { red[w] = h1; red[4 + w] = h2; red[8 + w] = h3; red[12 + w] = slo; }
  __syncthreads();
  if (tid == 0) {
    float s1 = red[0] + red[1] + red[2] + red[3];
    float s2 = red[4] + red[5] + red[6] + red[7];
    float s3 = red[8] + red[9] + red[10] + red[11];
    float sl = red[12] + red[13] + red[14] + red[15];
    low_out[r] = sl / (float)M3;
    high_out[r] = sqrtf(s1) + sqrtf(s2) + sqrtf(s3);
  }
}

// one thread per log-gamma draw: t in [0, TOT) = alpha-a, [TOT, 2*TOT) = alpha-b
__global__ __launch_bounds__(64) void gamma_kernel(
    const float* __restrict__ u_low, const float* __restrict__ u_high,
    const float* __restrict__ i_low, const float* __restrict__ i_high,
    float* __restrict__ lgbuf, K2 kAu, K2 kBu, K2 kAi, K2 kBi) {
  const int TOT = NUM_U + NUM_I;
  int t = blockIdx.x * 64 + threadIdx.x;
  if (t >= 2 * TOT) return;
  int ab = t >= TOT ? 1 : 0;
  int ent = ab ? t - TOT : t;
  float low, high;
  K2 key;
  if (ent < NUM_U) {
    low = u_low[ent]; high = u_high[ent];
    key = elem_key(ab ? kBu : kAu, (uint32_t)ent, (uint32_t)NUM_U);
  } else {
    int j = ent - NUM_U;
    low = i_low[j]; high = i_high[j];
    key = elem_key(ab ? kBi : kAi, (uint32_t)j, (uint32_t)NUM_I);
  }
  float a1 = fmaxf(low, 1e-6f);
  float a2 = fmaxf(high, 1e-6f);
  float s = a1 + a2;
  float alpha = ab ? (10.0f * (a2 / s)) : (10.0f * (a1 / s));
  lgbuf[t] = log_gamma_sample(key, alpha);
}

__global__ __launch_bounds__(256) void combine_kernel(
    const float* __restrict__ lgbuf, float* __restrict__ out) {
  const int TOT = NUM_U + NUM_I;
  int t = blockIdx.x * 256 + threadIdx.x;
  if (t >= TOT) return;
  float lga = lgbuf[t];
  float lgb = lgbuf[TOT + t];
  float m = fmaxf(lga, lgb);
  float na = expf(lga - m);
  float nb = expf(lgb - m);
  float w = na / (na + nb);
  int o0, o1;
  if (t < NUM_U) { o0 = OFF_UPW + t; o1 = OFF_UMW + t; }
  else { int j = t - NUM_U; o0 = OFF_IPW + j; o1 = OFF_IMW + j; }
  out[o0] = w;
  out[o1] = 1.0f - w;
}

// ---------------- host ----------------
extern "C" void kernel_launch(void* const* d_in, const int* in_sizes, int n_in,
                              void* d_out, int out_size, void* d_ws, size_t ws_size,
                              hipStream_t stream) {
  const int* user_idx = (const int*)d_in[0];
  const int* item_idx = (const int*)d_in[1];
  const float* values = (const float*)d_in[2];
  const int NNZ = in_sizes[0];

  char* ws = (char*)d_ws;
  double* nrm2_pop = (double*)(ws + 0);
  double* nrm2_act = (double*)(ws + 8);
  float* lgbuf = (float*)(ws + 16);          // 2*(NUM_U+NUM_I) floats
  float* pop = (float*)(ws + 229392);        // RAW pop
  float* act = (float*)(ws + 262160);        // RAW act
  int* fill_u = (int*)(ws + 327696);
  int* fill_i = (int*)(ws + 393232);
  float* u_low = (float*)(ws + 426000);
  float* u_high = (float*)(ws + 491536);
  float* i_low = (float*)(ws + 557072);
  float* i_high = (float*)(ws + 589840);
  uint32_t* klist_u = (uint32_t*)(ws + 622608);    // row-major NUM_U x CAP_U
  uint32_t* klist_i = (uint32_t*)(ws + 11108368);  // row-major NUM_I x CAP_I
  float* out = (float*)d_out;

  // host-side key derivation: root=key(42)=(0,42); ku,ki=split(root); then
  // (key_a,key_b)=split(k) inside beta for each side.
  K2 root; root.a = 0u; root.b = 42u;
  K2 ku, ki, kAu, kBu, kAi, kBi;
  split2(root, ku, ki);
  split2(ku, kAu, kBu);
  split2(ki, kAi, kBi);

  init_kernel<<<1, 256, 0, stream>>>((ull*)ws);

  // bucketed fill: items need 128*4 + 128*256*4 = 131584 B LDS (uniform max)
  constexpr int BF_SHM = IB_ROWS * 4 + IB_ROWS * CAP_I * 4;
  hipFuncSetAttribute((const void*)bucket_fill_kernel,
                      hipFuncAttributeMaxDynamicSharedMemorySize, BF_SHM);
  bucket_fill_kernel<<<N_IBUCKET + N_UBUCKET, 256, BF_SHM, stream>>>(
      user_idx, item_idx, NNZ, fill_u, fill_i, klist_u, klist_i);

  pop_wave_kernel<<<NUM_I / 4, 256, 0, stream>>>(fill_i, klist_i, values, pop, nrm2_pop);
  act_wave_kernel<<<NUM_U / 4, 256, 0, stream>>>(fill_u, klist_u, item_idx, values,
                                                 pop, nrm2_pop, act, nrm2_act);

  // users: 20480 B -> 8 blocks/CU; items: 39808 B -> 4 blocks/CU
  constexpr int U_SHM = dwt_shm_bytes(8192, 4098, 2051, 1028, CAP_U);
  constexpr int I_SHM = dwt_shm_bytes(16384, 8194, 4099, 2052, CAP_I);
  hipFuncSetAttribute((const void*)dwt_rows_kernel<8192, 4098, 2051, 1028, CAP_U>,
                      hipFuncAttributeMaxDynamicSharedMemorySize, U_SHM);
  hipFuncSetAttribute((const void*)dwt_rows_kernel<16384, 8194, 4099, 2052, CAP_I>,
                      hipFuncAttributeMaxDynamicSharedMemorySize, I_SHM);

  dwt_rows_kernel<8192, 4098, 2051, 1028, CAP_U><<<NUM_U, 256, U_SHM, stream>>>(
      klist_u, fill_u, item_idx, values, act, nrm2_act, u_low, u_high, out, OFF_ACT);
  dwt_rows_kernel<16384, 8194, 4099, 2052, CAP_I><<<NUM_I, 256, I_SHM, stream>>>(
      klist_i, fill_i, user_idx, values, pop, nrm2_pop, i_low, i_high, out, OFF_POP);

  const int TOT2 = 2 * (NUM_U + NUM_I);
  gamma_kernel<<<(TOT2 + 63) / 64, 64, 0, stream>>>(
      u_low, u_high, i_low, i_high, lgbuf, kAu, kBu, kAi, kBi);
  combine_kernel<<<(NUM_U + NUM_I + 255) / 256, 256, 0, stream>>>(lgbuf, out);
}

// Round 15
// 397.374 us; speedup vs baseline: 1.5225x; 1.5225x over previous
//
#include <hip/hip_runtime.h>
#include <stdint.h>

// ============================================================================
// PopularNicheGraphBuilder: segment-sums -> normalize -> per-row db3 DWT stats
// (in LDS) -> exact replication of jax.random.beta (threefry + Marsaglia-Tsang
// log-space gamma).
//
// Round 15 (on r14): bucket_fill retuned for latency hiding. r14 fixed the
// 14x write amplification (dense LDS->global dumps) but ran the scan with 4
// waves/CU on 192/256 CUs -> latency-bound at ~10 GB/s/WG. Now: 1024
// threads/WG (16 waves/CU), ILP-2 int4 loads, 256 buckets == 256 CUs
// (items 128x64 rows, users 128x128 rows), trip count 977 -> 122.
// Semantics unchanged (order-invariant consumers) -> bit-identical.
// ============================================================================
#define PARTITIONABLE 1

typedef unsigned long long ull;

#define NUM_U 16384
#define NUM_I 8192
#define CAP_U 160
#define CAP_I 256

#define IB_ROWS 64
#define UB_ROWS 128
#define N_IBUCKET (NUM_I / IB_ROWS)   // 128
#define N_UBUCKET (NUM_U / UB_ROWS)   // 128

// output layout
#define OFF_UPW 0
#define OFF_UMW 16384
#define OFF_IPW 32768
#define OFF_IMW 40960
#define OFF_ACT 49152
#define OFF_POP 65536

// ---------------- threefry2x32 ----------------
struct K2 { uint32_t a, b; };

__host__ __device__ inline void tf2x32(uint32_t k0, uint32_t k1, uint32_t& x0, uint32_t& x1) {
  const uint32_t ks2 = k0 ^ k1 ^ 0x1BD11BDAu;
  x0 += k0; x1 += k1;
#define TF_R(r) { x0 += x1; x1 = (x1 << (r)) | (x1 >> (32 - (r))); x1 ^= x0; }
  TF_R(13) TF_R(15) TF_R(26) TF_R(6)
  x0 += k1; x1 += ks2 + 1u;
  TF_R(17) TF_R(29) TF_R(16) TF_R(24)
  x0 += ks2; x1 += k0 + 2u;
  TF_R(13) TF_R(15) TF_R(26) TF_R(6)
  x0 += k0; x1 += k1 + 3u;
  TF_R(17) TF_R(29) TF_R(16) TF_R(24)
  x0 += k1; x1 += ks2 + 4u;
  TF_R(13) TF_R(15) TF_R(26) TF_R(6)
  x0 += ks2; x1 += k0 + 5u;
#undef TF_R
}

__host__ __device__ inline K2 tf_enc(K2 k, uint32_t x0, uint32_t x1) {
  tf2x32(k.a, k.b, x0, x1);
  K2 r; r.a = x0; r.b = x1; return r;
}

// split(key) -> 2 children
__host__ __device__ inline void split2(K2 k, K2& c0, K2& c1) {
#if PARTITIONABLE
  c0 = tf_enc(k, 0u, 0u);
  c1 = tf_enc(k, 0u, 1u);
#else
  K2 p = tf_enc(k, 0u, 2u);
  K2 q = tf_enc(k, 1u, 3u);
  c0.a = p.a; c0.b = q.a;
  c1.a = p.b; c1.b = q.b;
#endif
}

// split(key, 3)
__device__ inline void split3(K2 k, K2& c0, K2& c1, K2& c2) {
#if PARTITIONABLE
  c0 = tf_enc(k, 0u, 0u);
  c1 = tf_enc(k, 0u, 1u);
  c2 = tf_enc(k, 0u, 2u);
#else
  K2 p = tf_enc(k, 0u, 3u);
  K2 q = tf_enc(k, 1u, 4u);
  K2 r = tf_enc(k, 2u, 5u);
  c0.a = p.a; c0.b = q.a;
  c1.a = r.a; c1.b = p.b;
  c2.a = q.b; c2.b = r.b;
#endif
}

// scalar random_bits(key, 32, ())
__device__ inline uint32_t draw_bits(K2 k) {
  K2 e = tf_enc(k, 0u, 0u);
#if PARTITIONABLE
  return e.a ^ e.b;
#else
  return e.a;
#endif
}

// split(key, B)[i]
__device__ inline K2 elem_key(K2 k, uint32_t i, uint32_t B) {
#if PARTITIONABLE
  return tf_enc(k, 0u, i);
#else
  if (i < (B >> 1)) {
    K2 p = tf_enc(k, 2u * i, B + 2u * i);
    K2 q = tf_enc(k, 2u * i + 1u, B + 2u * i + 1u);
    K2 r; r.a = p.a; r.b = q.a; return r;
  } else {
    uint32_t j = 2u * i - B;
    K2 p = tf_enc(k, j, 2u * i);
    K2 q = tf_enc(k, j + 1u, 2u * i + 1u);
    K2 r; r.a = p.b; r.b = q.b; return r;
  }
#endif
}

__device__ inline float u01_bits(uint32_t b) {
  return __uint_as_float((b >> 9) | 0x3F800000u) - 1.0f;
}

// XLA ErfInv32 (Giles polynomial) -- matches lax.erf_inv on f32
__device__ inline float erfinv_f32(float x) {
  float w = -log1pf(-x * x);
  float p;
  if (w < 5.0f) {
    w = w - 2.5f;
    p = 2.81022636e-08f;
    p = fmaf(p, w, 3.43273939e-07f);
    p = fmaf(p, w, -3.5233877e-06f);
    p = fmaf(p, w, -4.39150654e-06f);
    p = fmaf(p, w, 0.00021858087f);
    p = fmaf(p, w, -0.00125372503f);
    p = fmaf(p, w, -0.00417768164f);
    p = fmaf(p, w, 0.246640727f);
    p = fmaf(p, w, 1.50140941f);
  } else {
    w = sqrtf(w) - 3.0f;
    p = -0.000200214257f;
    p = fmaf(p, w, 0.000100950558f);
    p = fmaf(p, w, 0.00134934322f);
    p = fmaf(p, w, -0.00367342844f);
    p = fmaf(p, w, 0.00573950773f);
    p = fmaf(p, w, -0.0076224613f);
    p = fmaf(p, w, 0.00943887047f);
    p = fmaf(p, w, 1.00167406f);
    p = fmaf(p, w, 2.83297682f);
  }
  return p * x;
}

// jax _gamma_one with log_space=True (Marsaglia-Tsang + boost)
__device__ float log_gamma_sample(K2 key, float alpha_orig) {
  const bool boost = (alpha_orig >= 1.0f);
  const float alpha = boost ? alpha_orig : (alpha_orig + 1.0f);
  const float d = alpha - 0.33333334f;
  const float c = 0.33333334f / sqrtf(d);

  K2 k0, sub;
  split2(key, k0, sub);
  const float u_boost = u01_bits(draw_bits(sub));

  K2 kcur = k0;
  float X = 0.0f, V = 1.0f, U = 2.0f;
  while ((U >= 1.0f - 0.0331f * (X * X)) &&
         (logf(U) >= X * 0.5f + d * ((1.0f - V) + logf(V)))) {
    K2 knext, xk, Uk;
    split3(kcur, knext, xk, Uk);
    kcur = knext;
    float x, v;
    K2 ik = xk;
    do {
      K2 in0, isub;
      split2(ik, in0, isub);
      ik = in0;
      float f = u01_bits(draw_bits(isub));
      // uniform(lo=nextafter(-1,0), hi=1): (hi-lo) rounds to exactly 2.0f
      float u = fmaxf(-0.99999994f, f * 2.0f + (-0.99999994f));
      x = 1.41421356f * erfinv_f32(u);   // sqrt(2) as f32
      v = 1.0f + x * c;
    } while (v <= 0.0f);
    X = x * x;
    V = (v * v) * v;
    U = u01_bits(draw_bits(Uk));
  }
  float lg = logf(d * V);
  if (!boost) lg += log1pf(-u_boost) / alpha_orig;
  return lg;
}

// ---------------- pipeline kernels ----------------

__global__ __launch_bounds__(256) void init_kernel(ull* __restrict__ nrm2pair) {
  int i = threadIdx.x;
  if (i < 2) nrm2pair[i] = 0ull;
}

// One workgroup per bucket: blocks [0, N_IBUCKET) = item buckets, rest =
// user buckets. 1024 threads scan the index array with ILP-2 int4 loads,
// LDS-append entries for owned rows, then dump region + counts densely.
__global__ __launch_bounds__(1024) void bucket_fill_kernel(
    const int* __restrict__ user, const int* __restrict__ item, int n,
    int* __restrict__ fu, int* __restrict__ fi,
    uint32_t* __restrict__ lu, uint32_t* __restrict__ li) {
  extern __shared__ uint32_t lsm[];
  const int bid = blockIdx.x;
  const int tid = threadIdx.x;
  const bool is_item = bid < N_IBUCKET;
  const int rows = is_item ? IB_ROWS : UB_ROWS;
  const int cap = is_item ? CAP_I : CAP_U;
  const int base = is_item ? bid * IB_ROWS : (bid - N_IBUCKET) * UB_ROWS;
  const int* __restrict__ src = is_item ? item : user;
  uint32_t* cnt = lsm;            // rows
  uint32_t* list = lsm + rows;    // rows * cap

  for (int i = tid; i < rows; i += 1024) cnt[i] = 0u;
  __syncthreads();

  const int4* src4 = (const int4*)src;
  const int n4 = n >> 2;
  for (int k4 = tid; k4 < n4; k4 += 2048) {
    int4 a = src4[k4];
    int k4b = k4 + 1024;
    bool hb = k4b < n4;
    int4 b;
    if (hb) b = src4[k4b];
    {
      int k0 = k4 << 2;
      int r0 = a.x - base, r1 = a.y - base, r2 = a.z - base, r3 = a.w - base;
      if ((unsigned)r0 < (unsigned)rows) { uint32_t q = atomicAdd(&cnt[r0], 1u); if ((int)q < cap) list[r0 * cap + (int)q] = (uint32_t)k0; }
      if ((unsigned)r1 < (unsigned)rows) { uint32_t q = atomicAdd(&cnt[r1], 1u); if ((int)q < cap) list[r1 * cap + (int)q] = (uint32_t)(k0 + 1); }
      if ((unsigned)r2 < (unsigned)rows) { uint32_t q = atomicAdd(&cnt[r2], 1u); if ((int)q < cap) list[r2 * cap + (int)q] = (uint32_t)(k0 + 2); }
      if ((unsigned)r3 < (unsigned)rows) { uint32_t q = atomicAdd(&cnt[r3], 1u); if ((int)q < cap) list[r3 * cap + (int)q] = (uint32_t)(k0 + 3); }
    }
    if (hb) {
      int k0 = k4b << 2;
      int r0 = b.x - base, r1 = b.y - base, r2 = b.z - base, r3 = b.w - base;
      if ((unsigned)r0 < (unsigned)rows) { uint32_t q = atomicAdd(&cnt[r0], 1u); if ((int)q < cap) list[r0 * cap + (int)q] = (uint32_t)k0; }
      if ((unsigned)r1 < (unsigned)rows) { uint32_t q = atomicAdd(&cnt[r1], 1u); if ((int)q < cap) list[r1 * cap + (int)q] = (uint32_t)(k0 + 1); }
      if ((unsigned)r2 < (unsigned)rows) { uint32_t q = atomicAdd(&cnt[r2], 1u); if ((int)q < cap) list[r2 * cap + (int)q] = (uint32_t)(k0 + 2); }
      if ((unsigned)r3 < (unsigned)rows) { uint32_t q = atomicAdd(&cnt[r3], 1u); if ((int)q < cap) list[r3 * cap + (int)q] = (uint32_t)(k0 + 3); }
    }
  }
  for (int k = (n4 << 2) + tid; k < n; k += 1024) {
    int r = src[k] - base;
    if ((unsigned)r < (unsigned)rows) { uint32_t q = atomicAdd(&cnt[r], 1u); if ((int)q < cap) list[r * cap + (int)q] = (uint32_t)k; }
  }
  __syncthreads();

  // dense dumps: klist region (contiguous) + counts
  uint32_t* gl = (is_item ? li : lu) + (size_t)base * cap;
  const int w4 = (rows * cap) >> 2;
  int4* gl4 = (int4*)gl;
  const int4* ls4 = (const int4*)list;
  for (int i = tid; i < w4; i += 1024) gl4[i] = ls4[i];
  int* fc = (is_item ? fi : fu) + base;
  for (int i = tid; i < rows; i += 1024) fc[i] = (int)cnt[i];
}

// one wave per item: exact int64 fixed-point sum of values over the item list.
// Writes RAW pop (normalization applied inline by consumers).
__global__ __launch_bounds__(256) void pop_wave_kernel(
    const int* __restrict__ fi, const uint32_t* __restrict__ li,
    const float* __restrict__ values,
    float* __restrict__ pop, double* __restrict__ nrm2) {
  __shared__ float red[4];
  int lane = threadIdx.x & 63, wid = threadIdx.x >> 6;
  int i = blockIdx.x * 4 + wid;
  int cnt = fi[i];
  int cr = cnt < CAP_I ? cnt : CAP_I;
  long long s = 0;
  for (int e = lane; e < cr; e += 64)
    s += (long long)llrintf(values[li[(size_t)i * CAP_I + e]] * 4294967296.0f);
  for (int o = 32; o > 0; o >>= 1) s += __shfl_down(s, o);
  if (lane == 0) {
    float svf = (float)((double)(ull)s * (1.0 / 4294967296.0));
    float p = svf * log1pf((float)cnt);
    pop[i] = p;
    red[wid] = p * p;
  }
  __syncthreads();
  if (threadIdx.x == 0)
    atomicAdd(nrm2, (double)(red[0] + red[1] + red[2] + red[3]));
}

// one wave per user: exact int64 fixed-point sum of act terms over the list.
// pop is RAW; normalized inline with the exact pop_norm expression.
__global__ __launch_bounds__(256) void act_wave_kernel(
    const int* __restrict__ fu, const uint32_t* __restrict__ lu,
    const int* __restrict__ item, const float* __restrict__ values,
    const float* __restrict__ pop, const double* __restrict__ nrm2_pop,
    float* __restrict__ act, double* __restrict__ nrm2) {
  __shared__ float red[4];
  int lane = threadIdx.x & 63, wid = threadIdx.x >> 6;
  int u = blockIdx.x * 4 + wid;
  int cnt = fu[u];
  int cr = cnt < CAP_U ? cnt : CAP_U;
  const float nrmp = sqrtf((float)(*nrm2_pop));
  const float dnp = nrmp + 1e-8f;
  long long s = 0;
  for (int e = lane; e < cr; e += 64) {
    uint32_t k = lu[(size_t)u * CAP_U + e];
    float pn = pop[item[k]] / dnp;                 // == pop_norm's v, bit-identical
    float term = values[k] / log1pf(pn + 1e-8f);
    s += (long long)llrintf(term * 16777216.0f);
  }
  for (int o = 32; o > 0; o >>= 1) s += __shfl_down(s, o);
  if (lane == 0) {
    float a = (float)((double)(ull)s * (1.0 / 16777216.0));
    act[u] = a;
    red[wid] = a * a;
  }
  __syncthreads();
  if (threadIdx.x == 0)
    atomicAdd(nrm2, (double)(red[0] + red[1] + red[2] + red[3]));
}

// ---------------- bit tricks ----------------
__device__ inline uint32_t evencomp(uint32_t x) {
  x = (x | (x >> 1)) & 0x55555555u;
  x = (x | (x >> 1)) & 0x33333333u;
  x = (x | (x >> 2)) & 0x0F0F0F0Fu;
  x = (x | (x >> 4)) & 0x00FF00FFu;
  x = (x | (x >> 8)) & 0x0000FFFFu;
  return x;
}
template <int NWIN>
__device__ inline uint32_t hword(const uint32_t* B, int i) {
  uint32_t a = (2 * i < NWIN) ? B[2 * i] : 0u;
  uint32_t b = (2 * i + 1 < NWIN) ? B[2 * i + 1] : 0u;
  return evencomp(a) | (evencomp(b) << 16);
}
template <int NWIN>
__device__ inline uint32_t tword(const uint32_t* B, int w) {
  uint32_t h = hword<NWIN>(B, w);
  uint32_t hp = (w > 0) ? hword<NWIN>(B, w - 1) : 0u;
  return h | (h << 1) | (h << 2) | (hp >> 31) | (hp >> 30);
}

// block-wide popcount prefix scan; entry+exit barriers inside. Returns total.
template <int NWORDS>
__device__ inline int scan_bits(const uint32_t* __restrict__ W, uint16_t* __restrict__ P,
                                int tid, int* __restrict__ isc, int* __restrict__ tot) {
  constexpr int WPT = (NWORDS + 255) / 256;
  __syncthreads();
  uint32_t w[WPT];
  int v = 0;
#pragma unroll
  for (int j = 0; j < WPT; ++j) {
    int idx = tid * WPT + j;
    w[j] = (idx < NWORDS) ? W[idx] : 0u;
    v += __popc(w[j]);
  }
  int lane = tid & 63, wid = tid >> 6;
  int incl = v;
  for (int off = 1; off < 64; off <<= 1) {
    int y = __shfl_up(incl, off, 64);
    if (lane >= off) incl += y;
  }
  if (lane == 63) isc[wid] = incl;
  __syncthreads();
  int base = 0;
  for (int ww = 0; ww < wid; ++ww) base += isc[ww];
  int run = base + incl - v;
#pragma unroll
  for (int j = 0; j < WPT; ++j) {
    int idx = tid * WPT + j;
    if (idx < NWORDS) P[idx] = (uint16_t)run;
    run += __popc(w[j]);
  }
  if (tid == 255) *tot = run;
  __syncthreads();
  return *tot;
}

// invert (T,P) into a worklist of touched positions, ascending
template <int NWORDS>
__device__ inline void build_wl(const uint32_t* __restrict__ T, const uint16_t* __restrict__ P,
                                uint16_t* __restrict__ wl, int tid) {
  for (int w = tid; w < NWORDS; w += 256) {
    uint32_t bits = T[w];
    int r0 = P[w], i = 0;
    while (bits) {
      int b = __ffs(bits) - 1; bits &= bits - 1u;
      wl[r0 + i] = (uint16_t)((w << 5) + b);
      ++i;
    }
  }
}

// 6-tap gather at output m from (bitmap B, prefix P, compacted values V)
template <int NIN>
__device__ inline void gather6(const uint32_t* __restrict__ B, const uint16_t* __restrict__ P,
                               const float* __restrict__ V, int m,
                               float& lo_o, float& hi_o) {
  int c0 = 2 * m - 4; c0 = c0 < 0 ? 0 : c0;
  int c1 = 2 * m + 1; c1 = c1 > NIN - 1 ? NIN - 1 : c1;
  int w0 = c0 >> 5, w1 = c1 >> 5;
  uint32_t b0 = B[w0];
  uint32_t mlo = ~((1u << (c0 & 31)) - 1u);
  uint32_t mhi = (uint32_t)(((uint64_t)1u << ((c1 & 31) + 1)) - 1u);
  uint32_t sel0, sel1; uint32_t b1 = 0;
  if (w1 == w0) { sel0 = b0 & mlo & mhi; sel1 = 0u; }
  else { b1 = B[w1]; sel0 = b0 & mlo; sel1 = b1 & mhi; }
  float tv0 = 0.0f, tv1 = 0.0f, tv2 = 0.0f, tv3 = 0.0f, tv4 = 0.0f, tv5 = 0.0f;
  int tp1 = 2 * m + 1;
  uint32_t s = sel0;
  while (s) {
    int b = __ffs(s) - 1; s &= s - 1u;
    int c = (w0 << 5) + b;
    int idx = (int)P[w0] + __popc(b0 & ((1u << b) - 1u));
    float v = V[idx];
    int t = tp1 - c;
    if (t == 0) tv0 = v; else if (t == 1) tv1 = v; else if (t == 2) tv2 = v;
    else if (t == 3) tv3 = v; else if (t == 4) tv4 = v; else tv5 = v;
  }
  s = sel1;
  while (s) {
    int b = __ffs(s) - 1; s &= s - 1u;
    int c = (w1 << 5) + b;
    int idx = (int)P[w1] + __popc(b1 & ((1u << b) - 1u));
    float v = V[idx];
    int t = tp1 - c;
    if (t == 0) tv0 = v; else if (t == 1) tv1 = v; else if (t == 2) tv2 = v;
    else if (t == 3) tv3 = v; else if (t == 4) tv4 = v; else tv5 = v;
  }
  float lo = 0.0f, hi = 0.0f;
  lo += 0.035226291882100656f * tv0;  hi += -0.3326705529509569f * tv0;
  lo += -0.08544127388224149f * tv1;  hi += 0.8068915093133388f * tv1;
  lo += -0.13501102001039084f * tv2;  hi += -0.4598775021193313f * tv2;
  lo += 0.4598775021193313f * tv3;    hi += -0.13501102001039084f * tv3;
  lo += 0.8068915093133388f * tv4;    hi += 0.08544127388224149f * tv4;
  lo += 0.3326705529509569f * tv5;    hi += 0.035226291882100656f * tv5;
  lo_o = lo; hi_o = hi;
}

__device__ inline int rank_of(const uint32_t* __restrict__ B, const uint16_t* __restrict__ P,
                              int m) {
  int w = m >> 5;
  return (int)P[w] + __popc(B[w] & ((1u << (m & 31)) - 1u));
}

constexpr int align4c(int x) { return (x + 3) & ~3; }
constexpr int cmax(int a, int b) { return a > b ? a : b; }

// LDS bytes for the worklist DWT kernel (mirrors device layout)
constexpr int dwt_shm_bytes(int NCOLS, int M1, int M2, int M3, int CAP) {
  int NW = NCOLS / 32, NW1 = (M1 + 31) / 32, NW2 = (M2 + 31) / 32, NW3 = (M3 + 31) / 32;
  int SZ_RB = cmax(cmax(align4c(NW * 4 + NW * 2), align4c(NW2 * 4 + 4 * CAP * 2)),
                   align4c(5 * CAP * 2));
  int SZ_RC = cmax(align4c(NW1 * 4 + NW1 * 2), align4c(NW3 * 4 + NW3 * 2 + NW2 * 2));
  return (M1 + 12) * 4 + CAP * 4 + SZ_RB + SZ_RC + align4c(3 * CAP * 2) + 64;
}

// per-row 3-level db3 DWT stats, worklist-driven, register-carry staging.
// klist row-major: entry q of row r at klist[r * CAP + q].
// scale_raw + nrm2 -> scale computed inline; tid0 writes out[outoff + r].
template <int NCOLS, int M1, int M2, int M3, int CAP>
__global__ __launch_bounds__(256) void dwt_rows_kernel(
    const uint32_t* __restrict__ klist, const int* __restrict__ rowlen,
    const int* __restrict__ colsrc, const float* __restrict__ values,
    const float* __restrict__ scale_raw, const double* __restrict__ nrm2,
    float* __restrict__ low_out, float* __restrict__ high_out,
    float* __restrict__ out, int outoff) {
  static_assert(CAP <= 256, "register-carry staging requires CAP <= blockDim");
  constexpr int NW = NCOLS / 32;
  constexpr int NW1 = (M1 + 31) / 32;
  constexpr int NW2 = (M2 + 31) / 32;
  constexpr int NW3 = (M3 + 31) / 32;
  constexpr uint32_t MK1 = (M1 & 31) ? ((1u << (M1 & 31)) - 1u) : 0xFFFFFFFFu;
  constexpr uint32_t MK2 = (M2 & 31) ? ((1u << (M2 & 31)) - 1u) : 0xFFFFFFFFu;
  constexpr uint32_t MK3 = (M3 & 31) ? ((1u << (M3 & 31)) - 1u) : 0xFFFFFFFFu;
  constexpr int SZ_RB = cmax(cmax(align4c(NW * 4 + NW * 2), align4c(NW2 * 4 + 4 * CAP * 2)),
                             align4c(5 * CAP * 2));
  constexpr int SZ_RC = cmax(align4c(NW1 * 4 + NW1 * 2), align4c(NW3 * 4 + NW3 * 2 + NW2 * 2));

  extern __shared__ char smroot[];
  float* buf = (float*)smroot;                       // (M1+12) f; data at +4
  char* pA = smroot + (M1 + 12) * 4;
  int* slot = (int*)pA;                              // CAP (sval aliases)
  float* sval = (float*)pA;
  char* pB = pA + CAP * 4;                           // region B (phase union)
  uint32_t* bitmap = (uint32_t*)pB;                  //   ph1: bitmap NW
  uint16_t* prefix = (uint16_t*)(pB + NW * 4);       //   ph1: prefix NW u16
  uint32_t* T2 = (uint32_t*)pB;                      //   ph2: T2 NW2
  uint16_t* wl2 = (uint16_t*)(pB + NW2 * 4);         //   ph2: wl2 4*CAP u16
  uint16_t* wl3 = (uint16_t*)pB;                     //   ph3: wl3 5*CAP u16
  char* pC = pB + SZ_RB;                             // region C (phase union)
  uint32_t* T1 = (uint32_t*)pC;                      //   ph1: T1 NW1
  uint16_t* p1 = (uint16_t*)(pC + NW1 * 4);          //   ph1: p1 NW1 u16
  uint32_t* T3 = (uint32_t*)pC;                      //   ph2+: T3 NW3
  uint16_t* p3 = (uint16_t*)(pC + NW3 * 4);          //   ph2+: p3 NW3 u16
  uint16_t* p2 = (uint16_t*)(pC + NW3 * 4 + NW3 * 2);//   ph2: p2 NW2 u16
  char* pD = pC + SZ_RC;
  uint16_t* wl1 = (uint16_t*)pD;                     // wl1 3*CAP u16
  char* pE = pD + align4c(3 * CAP * 2);              // 64 B scratch
  int* isc = (int*)pE;                               //   scans: isc[4], tot
  int* tot = isc + 4;
  float* red = (float*)pE;                           //   final: red[16]

  const int r = blockIdx.x;
  const int tid = threadIdx.x;
  // inline normalization (bit-identical to the old norm kernels)
  const float nrm = sqrtf((float)(*nrm2));
  const float snv = scale_raw[r] / (nrm + 1e-8f);
  const float scale = 1.0f + snv;
  if (tid == 0) out[outoff + r] = snv;
  int n = rowlen[r];
  if (n > CAP) n = CAP;

  // s0: init
  {
    constexpr int NB4 = (M1 + 12) / 4;
    float4 z; z.x = 0.0f; z.y = 0.0f; z.z = 0.0f; z.w = 0.0f;
    for (int i = tid; i < NB4; i += 256) ((float4*)buf)[i] = z;
    for (int i = NB4 * 4 + tid; i < M1 + 12; i += 256) buf[i] = 0.0f;
  }
  for (int i = tid; i < NW; i += 256) bitmap[i] = 0u;
  if (tid < CAP) slot[tid] = 0;
  __syncthreads();

  // s1: register-carry staging (<=1 entry per thread) + column bitmap
  const bool have = tid < n;
  uint32_t my_k = 0; int my_c = 0; float my_v = 0.0f;
  if (have) {
    my_k = klist[(size_t)r * CAP + tid];
    my_c = colsrc[my_k];
    my_v = values[my_k] * scale;
    atomicOr(&bitmap[my_c >> 5], 1u << (my_c & 31));
  }
  // s2: prefix over bitmap (entry barrier orders s1)
  scan_bits<NW>(bitmap, prefix, tid, isc, tot);

  // s3: O(n) dedup -- winner = max original index (XLA last-wins scatter)
  int my_rank = 0;
  if (have) {
    my_rank = rank_of(bitmap, prefix, my_c);
    atomicMax(&slot[my_rank], (int)my_k + 1);
  }
  __syncthreads();

  // s4: winner self-writes its value (race-free: unique winner per rank)
  if (have && slot[my_rank] == (int)my_k + 1) sval[my_rank] = my_v;
  // build T1 (masked at M1)
  for (int w = tid; w < NW1; w += 256) {
    uint32_t t = tword<NW>(bitmap, w);
    if (w == NW1 - 1) t &= MK1;
    T1[w] = t;
  }
  // s5: prefix over T1 (entry barrier orders s4)
  const int n1 = scan_bits<NW1>(T1, p1, tid, isc, tot);
  // s6: worklist 1
  build_wl<NW1>(T1, p1, wl1, tid);
  __syncthreads();

  // s7: LEVEL 1 -- worklist gather from (bitmap, prefix, sval) into buf
  float h1 = 0.0f;
  for (int idx = tid; idx < n1; idx += 256) {
    int m = wl1[idx];
    float lo, hi;
    gather6<NCOLS>(bitmap, prefix, sval, m, lo, hi);
    buf[4 + m] = lo;
    h1 += hi * hi;
  }
  __syncthreads();   // buf L1 writes done; bitmap/prefix/sval dead

  // s8: T2 from T1 (region B over the dead bitmap), masked at M2
  for (int w = tid; w < NW2; w += 256) {
    uint32_t t = tword<NW1>(T1, w);
    if (w == NW2 - 1) t &= MK2;
    T2[w] = t;
  }
  // s9: prefix over T2 (entry barrier orders s8)
  const int n2 = scan_bits<NW2>(T2, p2, tid, isc, tot);
  // s10: worklist 2 + T3 from T2 (region C over dead T1), masked at M3
  build_wl<NW2>(T2, p2, wl2, tid);
  for (int w = tid; w < NW3; w += 256) {
    uint32_t t = tword<NW2>(T2, w);
    if (w == NW3 - 1) t &= MK3;
    T3[w] = t;
  }
  __syncthreads();

  // s11: LEVEL 2 -- worklist, in-place batched read->barrier->write
  float h2 = 0.0f;
  {
    int nb = (n2 + 255) >> 8;
    for (int b = 0; b < nb; ++b) {
      int idx = (b << 8) + tid;
      bool ok = idx < n2;
      int m = ok ? wl2[idx] : 0;
      const float* s = buf + 2 * m + 5;
      float x0 = s[0], x1 = s[-1], x2 = s[-2], x3 = s[-3], x4 = s[-4], x5 = s[-5];
      __syncthreads();
      if (ok) {
        float lo = 0.0f, hi = 0.0f;
        lo += 0.035226291882100656f * x0;  hi += -0.3326705529509569f * x0;
        lo += -0.08544127388224149f * x1;  hi += 0.8068915093133388f * x1;
        lo += -0.13501102001039084f * x2;  hi += -0.4598775021193313f * x2;
        lo += 0.4598775021193313f * x3;    hi += -0.13501102001039084f * x3;
        lo += 0.8068915093133388f * x4;    hi += 0.08544127388224149f * x4;
        lo += 0.3326705529509569f * x5;    hi += 0.035226291882100656f * x5;
        buf[4 + m] = lo;
        h2 += hi * hi;
      }
    }
  }
  __syncthreads();
  // stale-clear: level-1 outputs inside [0,M2) not overwritten by level 2
  for (int idx = tid; idx < n1; idx += 256) {
    int m = wl1[idx];
    if (m < M2 && !((T2[m >> 5] >> (m & 31)) & 1u)) buf[4 + m] = 0.0f;
  }
  // stale gap [M2, M2+7]: level-1 outputs beyond level-2's range
  if (tid < 8) buf[4 + M2 + tid] = 0.0f;

  // s12: prefix over T3 (entry barrier orders stale writes)
  const int n3 = scan_bits<NW3>(T3, p3, tid, isc, tot);
  // s13: worklist 3 (region B; T2/p2/wl2 dead)
  build_wl<NW3>(T3, p3, wl3, tid);
  __syncthreads();

  // s14: LEVEL 3 -- worklist, accumulate only
  float h3 = 0.0f, slo = 0.0f;
  for (int idx = tid; idx < n3; idx += 256) {
    int m = wl3[idx];
    const float* s = buf + 2 * m + 5;
    float x0 = s[0], x1 = s[-1], x2 = s[-2], x3 = s[-3], x4 = s[-4], x5 = s[-5];
    float lo = 0.0f, hi = 0.0f;
    lo += 0.035226291882100656f * x0;  hi += -0.3326705529509569f * x0;
    lo += -0.08544127388224149f * x1;  hi += 0.8068915093133388f * x1;
    lo += -0.13501102001039084f * x2;  hi += -0.4598775021193313f * x2;
    lo += 0.4598775021193313f * x3;    hi += -0.13501102001039084f * x3;
    lo += 0.8068915093133388f * x4;    hi += 0.08544127388224149f * x4;
    lo += 0.3326705529509569f * x5;    hi += 0.035226291882100656f * x5;
    slo += lo;
    h3 += hi * hi;
  }

  // s15: reduce
  for (int o = 32; o > 0; o >>= 1) {
    h1 += __shfl_down(h1, o);
    h2 += __shfl_down(h2, o);
    h3 += __shfl_down(h3, o);
    slo += __shfl_down(slo, o);
  }
  __syncthreads();   // all scans done; red may overwrite isc/tot
  int w = tid >> 6, lane = tid & 63;
  if (lane == 0) { red[w] = h1; red[4 + w] = h2; red[8 + w] = h3; red[12 + w] = slo; }
  __syncthreads();
  if (tid == 0) {
    float s1 = red[0] + red[1] + red[2] + red[3];
    float s2 = red[4] + red[5] + red[6] + red[7];
    float s3 = red[8] + red[9] + red[10] + red[11];
    float sl = red[12] + red[13] + red[14] + red[15];
    low_out[r] = sl / (float)M3;
    high_out[r] = sqrtf(s1) + sqrtf(s2) + sqrtf(s3);
  }
}

// one thread per log-gamma draw: t in [0, TOT) = alpha-a, [TOT, 2*TOT) = alpha-b
__global__ __launch_bounds__(64) void gamma_kernel(
    const float* __restrict__ u_low, const float* __restrict__ u_high,
    const float* __restrict__ i_low, const float* __restrict__ i_high,
    float* __restrict__ lgbuf, K2 kAu, K2 kBu, K2 kAi, K2 kBi) {
  const int TOT = NUM_U + NUM_I;
  int t = blockIdx.x * 64 + threadIdx.x;
  if (t >= 2 * TOT) return;
  int ab = t >= TOT ? 1 : 0;
  int ent = ab ? t - TOT : t;
  float low, high;
  K2 key;
  if (ent < NUM_U) {
    low = u_low[ent]; high = u_high[ent];
    key = elem_key(ab ? kBu : kAu, (uint32_t)ent, (uint32_t)NUM_U);
  } else {
    int j = ent - NUM_U;
    low = i_low[j]; high = i_high[j];
    key = elem_key(ab ? kBi : kAi, (uint32_t)j, (uint32_t)NUM_I);
  }
  float a1 = fmaxf(low, 1e-6f);
  float a2 = fmaxf(high, 1e-6f);
  float s = a1 + a2;
  float alpha = ab ? (10.0f * (a2 / s)) : (10.0f * (a1 / s));
  lgbuf[t] = log_gamma_sample(key, alpha);
}

__global__ __launch_bounds__(256) void combine_kernel(
    const float* __restrict__ lgbuf, float* __restrict__ out) {
  const int TOT = NUM_U + NUM_I;
  int t = blockIdx.x * 256 + threadIdx.x;
  if (t >= TOT) return;
  float lga = lgbuf[t];
  float lgb = lgbuf[TOT + t];
  float m = fmaxf(lga, lgb);
  float na = expf(lga - m);
  float nb = expf(lgb - m);
  float w = na / (na + nb);
  int o0, o1;
  if (t < NUM_U) { o0 = OFF_UPW + t; o1 = OFF_UMW + t; }
  else { int j = t - NUM_U; o0 = OFF_IPW + j; o1 = OFF_IMW + j; }
  out[o0] = w;
  out[o1] = 1.0f - w;
}

// ---------------- host ----------------
extern "C" void kernel_launch(void* const* d_in, const int* in_sizes, int n_in,
                              void* d_out, int out_size, void* d_ws, size_t ws_size,
                              hipStream_t stream) {
  const int* user_idx = (const int*)d_in[0];
  const int* item_idx = (const int*)d_in[1];
  const float* values = (const float*)d_in[2];
  const int NNZ = in_sizes[0];

  char* ws = (char*)d_ws;
  double* nrm2_pop = (double*)(ws + 0);
  double* nrm2_act = (double*)(ws + 8);
  float* lgbuf = (float*)(ws + 16);          // 2*(NUM_U+NUM_I) floats
  float* pop = (float*)(ws + 229392);        // RAW pop
  float* act = (float*)(ws + 262160);        // RAW act
  int* fill_u = (int*)(ws + 327696);
  int* fill_i = (int*)(ws + 393232);
  float* u_low = (float*)(ws + 426000);
  float* u_high = (float*)(ws + 491536);
  float* i_low = (float*)(ws + 557072);
  float* i_high = (float*)(ws + 589840);
  uint32_t* klist_u = (uint32_t*)(ws + 622608);    // row-major NUM_U x CAP_U
  uint32_t* klist_i = (uint32_t*)(ws + 11108368);  // row-major NUM_I x CAP_I
  float* out = (float*)d_out;

  // host-side key derivation: root=key(42)=(0,42); ku,ki=split(root); then
  // (key_a,key_b)=split(k) inside beta for each side.
  K2 root; root.a = 0u; root.b = 42u;
  K2 ku, ki, kAu, kBu, kAi, kBi;
  split2(root, ku, ki);
  split2(ku, kAu, kBu);
  split2(ki, kAi, kBi);

  init_kernel<<<1, 256, 0, stream>>>((ull*)ws);

  // bucketed fill: users need 128*4 + 128*160*4 = 82432 B LDS (max of the two)
  constexpr int BF_SHM = UB_ROWS * 4 + UB_ROWS * CAP_U * 4;
  static_assert(BF_SHM >= IB_ROWS * 4 + IB_ROWS * CAP_I * 4, "item bucket must fit");
  hipFuncSetAttribute((const void*)bucket_fill_kernel,
                      hipFuncAttributeMaxDynamicSharedMemorySize, BF_SHM);
  bucket_fill_kernel<<<N_IBUCKET + N_UBUCKET, 1024, BF_SHM, stream>>>(
      user_idx, item_idx, NNZ, fill_u, fill_i, klist_u, klist_i);

  pop_wave_kernel<<<NUM_I / 4, 256, 0, stream>>>(fill_i, klist_i, values, pop, nrm2_pop);
  act_wave_kernel<<<NUM_U / 4, 256, 0, stream>>>(fill_u, klist_u, item_idx, values,
                                                 pop, nrm2_pop, act, nrm2_act);

  // users: 20480 B -> 8 blocks/CU; items: 39808 B -> 4 blocks/CU
  constexpr int U_SHM = dwt_shm_bytes(8192, 4098, 2051, 1028, CAP_U);
  constexpr int I_SHM = dwt_shm_bytes(16384, 8194, 4099, 2052, CAP_I);
  hipFuncSetAttribute((const void*)dwt_rows_kernel<8192, 4098, 2051, 1028, CAP_U>,
                      hipFuncAttributeMaxDynamicSharedMemorySize, U_SHM);
  hipFuncSetAttribute((const void*)dwt_rows_kernel<16384, 8194, 4099, 2052, CAP_I>,
                      hipFuncAttributeMaxDynamicSharedMemorySize, I_SHM);

  dwt_rows_kernel<8192, 4098, 2051, 1028, CAP_U><<<NUM_U, 256, U_SHM, stream>>>(
      klist_u, fill_u, item_idx, values, act, nrm2_act, u_low, u_high, out, OFF_ACT);
  dwt_rows_kernel<16384, 8194, 4099, 2052, CAP_I><<<NUM_I, 256, I_SHM, stream>>>(
      klist_i, fill_i, user_idx, values, pop, nrm2_pop, i_low, i_high, out, OFF_POP);

  const int TOT2 = 2 * (NUM_U + NUM_I);
  gamma_kernel<<<(TOT2 + 63) / 64, 64, 0, stream>>>(
      u_low, u_high, i_low, i_high, lgbuf, kAu, kBu, kAi, kBi);
  combine_kernel<<<(NUM_U + NUM_I + 255) / 256, 256, 0, stream>>>(lgbuf, out);
}